// Round 17
// baseline (91.007 us; speedup 1.0000x reference)
//
#include <hip/hip_runtime.h>
#include <float.h>

#define N_SRC 20000
#define N_TAR 20000
#define TPB 256                    // 4 waves/block
#define SPLITS 16                  // source splits (grid.y)
#define TILES 42                   // 32-source tiles/split; 16*42*32 = 21504 >= 20000
#define PACK_N (SPLITS * TILES * 64)   // 43008 half8 entries = 672 KB (L2-resident)
#define TGRP 40                    // 40 blocks * 4 waves * 4 strips * 32 = 20480 targets
#define FBLOCKS ((N_TAR + 255) / 256)

typedef _Float16 half8 __attribute__((ext_vector_type(8)));
typedef float floatx16 __attribute__((ext_vector_type(16)));

// q(t,s) = 0.5||s||^2 - t.s, so 0.5*d2 = 0.5||t||^2 + q (split-f16 slots in
// mfma_f32_32x32x16_f16; absmax 0 across r12-r16).
// r17: r15's no-LDS global-ring K-loop (LDS staging regressed twice: r13
// conflicts, r16 barrier+occupancy), with 4 strips per wave: 8 MFMA per
// 2 B-loads -> half the L2 traffic per MFMA, ~190 cyc independent compute
// per iteration so the depth-4 ring (~2 iters ahead) covers ~250 cyc L2
// latency. B pack in tile-lane order (entry = tile*64 + lane): lane-coalesced
// b128 loads, addressing is bp + tile*64.

#define DPP_MIN(v, ctrl) { \
    const int _s = __builtin_amdgcn_update_dpp( \
        __float_as_int(v), __float_as_int(v), (ctrl), 0xf, 0xf, false); \
    v = fminf(v, __int_as_float(_s)); }
#define COL_REDUCE(v) { \
    DPP_MIN(v, 0xB1)  /* quad_perm xor1 */ \
    DPP_MIN(v, 0x4E)  /* quad_perm xor2 */ \
    DPP_MIN(v, 0x141) /* row_half_mirror */ \
    DPP_MIN(v, 0x140) /* row_mirror */ \
    DPP_MIN(v, 0x142) /* row_bcast15 -> lanes 16-31 hold the 32-col min */ }

// prep: B pack in tile-lane order; zero out[0].
// entry i: tile_lin = i>>6, L = i&63 (half = L>>5), s = tile_lin*32 + (L&31)
__global__ __launch_bounds__(TPB) void nn_prep(
    const float* __restrict__ src, half8* __restrict__ pack,
    float* __restrict__ out)
{
    const int i = blockIdx.x * TPB + threadIdx.x;
    if (i == 0) out[0] = 0.f;
    if (i >= PACK_N) return;

    const int L = i & 63;
    const int hf = L >> 5;
    const int s = (i >> 6) * 32 + (L & 31);

    half8 f = {0, 0, 0, 0, 0, 0, 0, 0};
    if (s < N_SRC) {
        const float x = src[s * 3 + 0];
        const float y = src[s * 3 + 1];
        const float z = src[s * 3 + 2];
        const _Float16 xh = (_Float16)x, yh = (_Float16)y, zh = (_Float16)z;
        if (hf == 0) {
            const _Float16 xl = (_Float16)(x - (float)xh);
            const _Float16 yl = (_Float16)(y - (float)yh);
            f = (half8){xh, yh, zh, xh, yh, zh, xl, yl};
        } else {
            const _Float16 zl = (_Float16)(z - (float)zh);
            const float nrm = 0.5f * (x * x + y * y + z * z);
            const _Float16 nh = (_Float16)nrm;
            const _Float16 nl = (_Float16)(nrm - (float)nh);
            f = (half8){zl, nh, nl, 0, 0, 0, 0, 0};
        }
    } else if (hf == 1) {
        f = (half8){0, (_Float16)30000.f, 0, 0, 0, 0, 0, 0};  // pad: never the min
    }
    pack[i] = f;
}

#define MAKE_A(out_a, sidx) { \
    const int t = min((strip0 + (sidx)) * 32 + col, N_TAR - 1); \
    const float tx = tar[t * 3 + 0]; \
    const float ty = tar[t * 3 + 1]; \
    const float tz = tar[t * 3 + 2]; \
    const _Float16 txh = (_Float16)tx, tyh = (_Float16)ty, tzh = (_Float16)tz; \
    const _Float16 txl = (_Float16)(tx - (float)txh); \
    const _Float16 tyl = (_Float16)(ty - (float)tyh); \
    const _Float16 tzl = (_Float16)(tz - (float)tzh); \
    out_a = (half == 0) \
        ? (half8){-txh, -tyh, -tzh, -txl, -tyl, -tzl, -txh, -tyh} \
        : (half8){-tzh, (_Float16)1.f, (_Float16)1.f, 0, 0, 0, 0, 0}; }

#define TILE_STEP(aa, mm, t0_, t1_) { \
    const floatx16 d0 = __builtin_amdgcn_mfma_f32_32x32x16_f16(aa, t0_, zero, 0, 0, 0); \
    const floatx16 d1 = __builtin_amdgcn_mfma_f32_32x32x16_f16(aa, t1_, zero, 0, 0, 0); \
    _Pragma("unroll") \
    for (int i = 0; i < 16; ++i) mm[i] = fminf(mm[i], fminf(d0[i], d1[i])); }

#define STORE_STRIP(mm, sidx) { \
    _Pragma("unroll") \
    for (int i = 0; i < 16; ++i) { \
        const int row = (i & 3) + 8 * (i >> 2) + 4 * half; \
        const int t = min((strip0 + (sidx)) * 32 + row, N_TAR - 1); \
        prow[t] = mm[i]; } }   /* clamped rows rewrite identical values: benign */

__global__ __launch_bounds__(TPB) void nn_mfma(
    const half8* __restrict__ pack, const float* __restrict__ tar,
    float* __restrict__ part)
{
    const int tid  = threadIdx.x;
    const int lane = tid & 63;
    const int col  = lane & 31;
    const int half = (lane >> 5) & 1;
    const int wave = tid >> 6;

    // this wave's 4 strips of 32 targets
    const int strip0 = (blockIdx.x * 4 + wave) * 4;
    half8 a0, a1, a2, a3;
    MAKE_A(a0, 0) MAKE_A(a1, 1) MAKE_A(a2, 2) MAKE_A(a3, 3)

    // B walk: lane-coalesced, entry = split_base + tile*64 + lane
    const half8* bp = pack + (size_t)blockIdx.y * (TILES * 64) + lane;

    floatx16 m0, m1, m2, m3;
#pragma unroll
    for (int i = 0; i < 16; ++i) { m0[i] = FLT_MAX; m1[i] = FLT_MAX;
                                   m2[i] = FLT_MAX; m3[i] = FLT_MAX; }
    const floatx16 zero = {};

    // prefetch ring: 4 tiles (2 iterations ahead)
    half8 r0 = bp[0 * 64];
    half8 r1 = bp[1 * 64];
    half8 r2 = bp[2 * 64];
    half8 r3 = bp[3 * 64];
#pragma unroll 1
    for (int tp = 0; tp < TILES; tp += 2) {
        const int nx = min(tp + 4, TILES - 2);   // clamped (dup ok under min)
        const half8 n0 = bp[nx * 64];
        const half8 n1 = bp[nx * 64 + 64];
        TILE_STEP(a0, m0, r0, r1)
        TILE_STEP(a1, m1, r0, r1)
        TILE_STEP(a2, m2, r0, r1)
        TILE_STEP(a3, m3, r0, r1)
        r0 = r2; r1 = r3; r2 = n0; r3 = n1;
    }

#pragma unroll
    for (int i = 0; i < 16; ++i) {
        COL_REDUCE(m0[i]) COL_REDUCE(m1[i]) COL_REDUCE(m2[i]) COL_REDUCE(m3[i])
    }

    if (col == 16) {
        float* prow = part + (size_t)blockIdx.y * N_TAR;
        STORE_STRIP(m0, 0) STORE_STRIP(m1, 1) STORE_STRIP(m2, 2) STORE_STRIP(m3, 3)
    }
}

// combine the SPLITS mins per target, add 0.5||t||^2, reduce into out[0]
__global__ __launch_bounds__(256) void nn_finalize(
    const float* __restrict__ tar, const float* __restrict__ part,
    float* __restrict__ out)
{
    const int t = blockIdx.x * 256 + threadIdx.x;
    float contrib = 0.f;
    if (t < N_TAR) {
        float m = FLT_MAX;
#pragma unroll
        for (int c = 0; c < SPLITS; ++c) m = fminf(m, part[c * N_TAR + t]);
        const float tx = tar[t * 3 + 0];
        const float ty = tar[t * 3 + 1];
        const float tz = tar[t * 3 + 2];
        contrib = 0.5f * (tx * tx + ty * ty + tz * tz) + m;
    }
    for (int off = 32; off > 0; off >>= 1)
        contrib += __shfl_down(contrib, off);
    __shared__ float red[4];
    if ((threadIdx.x & 63) == 0) red[threadIdx.x >> 6] = contrib;
    __syncthreads();
    if (threadIdx.x == 0) {
        float s = 0.f;
#pragma unroll
        for (int w = 0; w < 4; ++w) s += red[w];
        atomicAdd(out, s);
    }
}

extern "C" void kernel_launch(void* const* d_in, const int* in_sizes, int n_in,
                              void* d_out, int out_size, void* d_ws, size_t ws_size,
                              hipStream_t stream) {
    const float* src = (const float*)d_in[0];  // [20000,3] fp32
    const float* tar = (const float*)d_in[1];  // [20000,3] fp32
    float* out = (float*)d_out;                // scalar fp32

    char* w = (char*)d_ws;
    float* part = (float*)w;                           // 16*20000*4 = 1.28 MB
    half8* pack = (half8*)(w + 2 * 1024 * 1024);       // 672 KB

    nn_prep<<<(PACK_N + TPB - 1) / TPB, TPB, 0, stream>>>(src, pack, out);
    dim3 grid1(TGRP, SPLITS);
    nn_mfma<<<grid1, TPB, 0, stream>>>(pack, tar, part);
    nn_finalize<<<FBLOCKS, 256, 0, stream>>>(tar, part, out);
}